// Round 1
// baseline (550.876 us; speedup 1.0000x reference)
//
#include <hip/hip_runtime.h>
#include <hip/hip_bf16.h>

// Problem constants (B, L, DM, DK, DV) from the reference.
#define B_  4
#define L_  4096
#define DM_ 1024
#define DK_ 128
#define DV_ 128

typedef __bf16 bf16x8 __attribute__((ext_vector_type(8)));
typedef float  f32x4  __attribute__((ext_vector_type(4)));

__device__ __forceinline__ float wred_max16(float v) {
    v = fmaxf(v, __shfl_xor(v, 1, 64));
    v = fmaxf(v, __shfl_xor(v, 2, 64));
    v = fmaxf(v, __shfl_xor(v, 4, 64));
    v = fmaxf(v, __shfl_xor(v, 8, 64));
    return v;
}
__device__ __forceinline__ float wred_sum16(float v) {
    v += __shfl_xor(v, 1, 64);
    v += __shfl_xor(v, 2, 64);
    v += __shfl_xor(v, 4, 64);
    v += __shfl_xor(v, 8, 64);
    return v;
}

// ---------------------------------------------------------------------------
// Kernel 1: projections. q = Q*WQ, k = K*WK (row-major bf16), v = V*WV stored
// TRANSPOSED as vT[b][vd][s] so the attention PV B-fragments are contiguous.
// Block = 256 thr (4 waves), each wave computes a 16x128 output tile.
// W chunk (32 d x 128 n) staged in LDS as [n][d] bf16, pad +8 (2-way = free).
// ---------------------------------------------------------------------------
__global__ __launch_bounds__(256) void proj_kernel(
    const float* __restrict__ Q, const float* __restrict__ K, const float* __restrict__ V,
    const float* __restrict__ WQ, const float* __restrict__ WK, const float* __restrict__ WV,
    __bf16* __restrict__ qb, __bf16* __restrict__ kb, __bf16* __restrict__ vT)
{
    const int mat = blockIdx.y;                       // 0=Q, 1=K, 2=V
    const float* X = (mat == 0) ? Q  : (mat == 1) ? K  : V;
    const float* W = (mat == 0) ? WQ : (mat == 1) ? WK : WV;

    __shared__ __bf16 w_lds[128][40];                 // [n][d-chunk], pad 32->40

    const int t    = threadIdx.x;
    const int w    = t >> 6;
    const int l    = t & 63;
    const int quad = l >> 4;
    const int c16  = l & 15;
    const int m0   = blockIdx.x * 64 + w * 16;        // this wave's 16 rows
    const int mrow = m0 + c16;                        // A-frag row (m = lane&15)

    f32x4 acc[8];
    for (int i = 0; i < 8; ++i) acc[i] = {0.f, 0.f, 0.f, 0.f};

    for (int dt = 0; dt < DM_ / 32; ++dt) {
        const int d0 = dt * 32;
        __syncthreads();                              // protect w_lds reuse
        // stage W[d0:d0+32][0:128] into w_lds[n][dd]  (coalesced over n)
        for (int i = 0; i < 16; ++i) {
            int idx = i * 256 + t;
            int n  = idx & 127;
            int dd = idx >> 7;
            w_lds[n][dd] = (__bf16)W[(d0 + dd) * DK_ + n];
        }
        __syncthreads();

        // A fragment: 8 consecutive fp32 of this lane's row, cvt to bf16
        const float* xp = &X[(size_t)mrow * DM_ + d0 + quad * 8];
        float4 x0 = *(const float4*)xp;
        float4 x1 = *(const float4*)(xp + 4);
        bf16x8 af;
        af[0] = (__bf16)x0.x; af[1] = (__bf16)x0.y; af[2] = (__bf16)x0.z; af[3] = (__bf16)x0.w;
        af[4] = (__bf16)x1.x; af[5] = (__bf16)x1.y; af[6] = (__bf16)x1.z; af[7] = (__bf16)x1.w;

        for (int nt = 0; nt < 8; ++nt) {
            // B[k=d][n]: lane reads W[d0+quad*8+j][nt*16+c16] = w_lds[n][d] contiguous
            bf16x8 bfv = *(const bf16x8*)&w_lds[nt * 16 + c16][quad * 8];
            acc[nt] = __builtin_amdgcn_mfma_f32_16x16x32_bf16(af, bfv, acc[nt], 0, 0, 0);
        }
    }

    // C/D layout: row = quad*4 + r, col = c16 (+16*nt)  [m89/m91 verified]
    if (mat < 2) {
        __bf16* outp = (mat == 0) ? qb : kb;
        for (int nt = 0; nt < 8; ++nt)
            for (int r = 0; r < 4; ++r) {
                int row = m0 + quad * 4 + r;
                int col = nt * 16 + c16;
                outp[(size_t)row * DK_ + col] = (__bf16)acc[nt][r];
            }
    } else {
        for (int nt = 0; nt < 8; ++nt)
            for (int r = 0; r < 4; ++r) {
                int row = m0 + quad * 4 + r;          // flat b*L + s
                int col = nt * 16 + c16;              // vd
                int b = row >> 12;                    // L_ = 4096
                int s = row & (L_ - 1);
                vT[((size_t)b * DV_ + col) * L_ + s] = (__bf16)acc[nt][r];
            }
    }
}

// ---------------------------------------------------------------------------
// Kernel 2: flash attention. Block = 128 thr (2 waves), each wave owns 16
// q-rows; loop over 64-key chunks. k-tile (64x128) and vT-tile (128x64)
// staged in LDS (+8 bf16 pad -> 2-way bank aliasing, free). Online softmax:
// per-row m/l replicated across the 16-lane group; P goes C-layout -> LDS
// (bf16) -> A-layout fragments for PV. Denominator summed from the ROUNDED
// bf16 P so numerator/denominator are consistent.
// ---------------------------------------------------------------------------
__global__ __launch_bounds__(128) void attn_kernel(
    const __bf16* __restrict__ qb, const __bf16* __restrict__ kb,
    const __bf16* __restrict__ vT, const int* __restrict__ mask,
    float* __restrict__ out)
{
    __shared__ __bf16 k_lds[64][136];    // 64 keys x 128 d   (+8 pad)
    __shared__ __bf16 v_lds[128][72];    // 128 vd  x 64 s    (+8 pad)
    __shared__ __bf16 p_lds[2][16][72];  // per-wave P: 16 rows x 64 keys

    const int t    = threadIdx.x;
    const int w    = t >> 6;
    const int l    = t & 63;
    const int quad = l >> 4;
    const int c16  = l & 15;
    const int b    = blockIdx.y;
    const int m0   = blockIdx.x * 32 + w * 16;
    const size_t bL = (size_t)b * L_;

    // q fragments for this wave's 16 rows, all 128 d (A-layout: m = lane&15)
    bf16x8 qf[4];
    {
        const __bf16* qrow = &qb[(bL + m0 + c16) * DK_];
        for (int dt = 0; dt < 4; ++dt)
            qf[dt] = *(const bf16x8*)&qrow[dt * 32 + quad * 8];
    }

    f32x4 o[8];
    for (int i = 0; i < 8; ++i) o[i] = {0.f, 0.f, 0.f, 0.f};
    float mst[4], lst[4];
    for (int r = 0; r < 4; ++r) { mst[r] = -1e30f; lst[r] = 0.f; }

    const float sm_scale = 0.088388347648318447f;  // 1/sqrt(DK)

    for (int sc = 0; sc < L_ / 64; ++sc) {
        const int s0 = sc * 64;
        __syncthreads();  // previous chunk's LDS reads done before re-staging
        // stage K chunk (64 x 128 bf16): 16B per thread x 8
        for (int i = 0; i < 8; ++i) {
            int c  = i * 128 + t;
            int kr = c >> 4, c8 = (c & 15) << 3;
            *(int4*)&k_lds[kr][c8] = *(const int4*)&kb[(bL + s0 + kr) * DK_ + c8];
        }
        // stage vT chunk (128 x 64 bf16)
        for (int i = 0; i < 8; ++i) {
            int c  = i * 128 + t;
            int vr = c >> 3, s8 = (c & 7) << 3;
            *(int4*)&v_lds[vr][s8] = *(const int4*)&vT[((size_t)b * DV_ + vr) * L_ + s0 + s8];
        }
        __syncthreads();

        // ---- S = q . k^T  (16 rows x 64 keys) ----
        f32x4 sacc[4];
        for (int nt = 0; nt < 4; ++nt) sacc[nt] = {0.f, 0.f, 0.f, 0.f};
        for (int dt = 0; dt < 4; ++dt)
            for (int nt = 0; nt < 4; ++nt) {
                // B[k=d][n=s]: lane reads k[s0+c16][d] -> A-like contiguous load
                bf16x8 kf = *(const bf16x8*)&k_lds[nt * 16 + c16][dt * 32 + quad * 8];
                sacc[nt] = __builtin_amdgcn_mfma_f32_16x16x32_bf16(qf[dt], kf, sacc[nt], 0, 0, 0);
            }

        // mask (faithful: mask==1 keep else -inf; order vs scale is equivalent)
        int mk[4];
        for (int nt = 0; nt < 4; ++nt) mk[nt] = mask[bL + s0 + nt * 16 + c16];
        float sv[4][4];
        for (int nt = 0; nt < 4; ++nt)
            for (int r = 0; r < 4; ++r) {
                float s = sacc[nt][r] * sm_scale;
                sv[nt][r] = (mk[nt] == 1) ? s : -1e30f;
            }

        // ---- online softmax (row = quad*4 + r; cols across 16-lane group) ----
        float alpha[4];
        for (int r = 0; r < 4; ++r) {
            float cm = fmaxf(fmaxf(sv[0][r], sv[1][r]), fmaxf(sv[2][r], sv[3][r]));
            cm = wred_max16(cm);
            float nm = fmaxf(mst[r], cm);
            alpha[r] = __expf(mst[r] - nm);
            float psum = 0.f;
            for (int nt = 0; nt < 4; ++nt) {
                float p = __expf(sv[nt][r] - nm);
                __bf16 pbv = (__bf16)p;
                p_lds[w][quad * 4 + r][nt * 16 + c16] = pbv;  // C-layout -> LDS
                psum += (float)pbv;                            // sum the ROUNDED p
            }
            psum = wred_sum16(psum);
            lst[r] = lst[r] * alpha[r] + psum;
            mst[r] = nm;
        }
        // wave-local ordering: P writes visible before A-frag reads
        __asm__ volatile("s_waitcnt lgkmcnt(0)" ::: "memory");

        for (int vt = 0; vt < 8; ++vt)
            for (int r = 0; r < 4; ++r)
                o[vt][r] *= alpha[r];

        // ---- O += P . V ----
        for (int kt = 0; kt < 2; ++kt) {
            // A[m=lane&15][k=quad*8+j] from wave-private P buffer
            bf16x8 pf = *(const bf16x8*)&p_lds[w][c16][kt * 32 + quad * 8];
            for (int vt = 0; vt < 8; ++vt) {
                // B[k=s][n=vd]: lane reads vT[vd=vt*16+c16][s] contiguous
                bf16x8 vf = *(const bf16x8*)&v_lds[vt * 16 + c16][kt * 32 + quad * 8];
                o[vt] = __builtin_amdgcn_mfma_f32_16x16x32_bf16(pf, vf, o[vt], 0, 0, 0);
            }
        }
    }

    // epilogue: normalize, fp32 store
    float rinv[4];
    for (int r = 0; r < 4; ++r) rinv[r] = 1.0f / lst[r];
    for (int vt = 0; vt < 8; ++vt)
        for (int r = 0; r < 4; ++r) {
            int row = m0 + quad * 4 + r;
            int col = vt * 16 + c16;
            out[(bL + row) * DV_ + col] = o[vt][r] * rinv[r];
        }
}

extern "C" void kernel_launch(void* const* d_in, const int* in_sizes, int n_in,
                              void* d_out, int out_size, void* d_ws, size_t ws_size,
                              hipStream_t stream) {
    const float* Q    = (const float*)d_in[0];
    const float* K    = (const float*)d_in[1];
    const float* V    = (const float*)d_in[2];
    const int*   mask = (const int*)d_in[3];
    const float* WQ   = (const float*)d_in[4];
    const float* WK   = (const float*)d_in[5];
    const float* WV   = (const float*)d_in[6];
    float* out = (float*)d_out;

    // workspace: qb (4MB) | kb (4MB) | vT (4MB), all bf16
    __bf16* qb = (__bf16*)d_ws;
    __bf16* kb = qb + (size_t)B_ * L_ * DK_;
    __bf16* vT = kb + (size_t)B_ * L_ * DK_;

    // projections: grid.x = row tiles (16384/64), grid.y = {Q,K,V}
    proj_kernel<<<dim3((B_ * L_) / 64, 3), 256, 0, stream>>>(Q, K, V, WQ, WK, WV, qb, kb, vT);
    // attention: grid.x = q tiles (L/32), grid.y = batch
    attn_kernel<<<dim3(L_ / 32, B_), 128, 0, stream>>>(qb, kb, vT, mask, out);
}

// Round 2
// 508.048 us; speedup vs baseline: 1.0843x; 1.0843x over previous
//
#include <hip/hip_runtime.h>
#include <hip/hip_bf16.h>

#define B_  4
#define L_  4096
#define DM_ 1024
#define DK_ 128
#define DV_ 128

typedef __bf16 bf16x8 __attribute__((ext_vector_type(8)));
typedef float  f32x4  __attribute__((ext_vector_type(4)));

__device__ __forceinline__ float wred_max16(float v) {
    v = fmaxf(v, __shfl_xor(v, 1, 64));
    v = fmaxf(v, __shfl_xor(v, 2, 64));
    v = fmaxf(v, __shfl_xor(v, 4, 64));
    v = fmaxf(v, __shfl_xor(v, 8, 64));
    return v;
}
__device__ __forceinline__ float wred_sum16(float v) {
    v += __shfl_xor(v, 1, 64);
    v += __shfl_xor(v, 2, 64);
    v += __shfl_xor(v, 4, 64);
    v += __shfl_xor(v, 8, 64);
    return v;
}

// ---------------------------------------------------------------------------
// Kernel 0: transpose+cast W (1024x128 fp32) -> WT (128x1024 bf16), 3 mats.
// Tiny (1.5 MB read); LDS transpose for coalesced in/out.
// ---------------------------------------------------------------------------
__global__ __launch_bounds__(256) void wt_kernel(
    const float* __restrict__ WQ, const float* __restrict__ WK,
    const float* __restrict__ WV, __bf16* __restrict__ WT)
{
    const int mat = blockIdx.y;
    const float* W = (mat == 0) ? WQ : (mat == 1) ? WK : WV;
    __bf16* Wt = WT + (size_t)mat * DK_ * DM_;

    __shared__ float lds[DK_][33];              // [n][dd], +1 pad
    const int t  = threadIdx.x;
    const int d0 = blockIdx.x * 32;

    for (int i = 0; i < 16; ++i) {
        int idx = i * 256 + t;
        int dd = idx >> 7, n = idx & 127;       // coalesced over n
        lds[n][dd] = W[(size_t)(d0 + dd) * DK_ + n];
    }
    __syncthreads();
    for (int i = 0; i < 16; ++i) {
        int idx = i * 256 + t;
        int n = idx >> 5, dd = idx & 31;        // coalesced over dd
        Wt[(size_t)n * DM_ + d0 + dd] = (__bf16)lds[n][dd];
    }
}

// ---------------------------------------------------------------------------
// Kernel 1: projections, LDS-free / barrier-free. B-fragments come straight
// from WT[n][d] bf16 as contiguous 16 B loads (L1/L2-cached, 8 KB/dt working
// set shared by all resident waves). X is streamed fp32->bf16 in registers.
// q,k row-major bf16; v stored transposed vT[b][vd][s].
// ---------------------------------------------------------------------------
__global__ __launch_bounds__(256) void proj_kernel(
    const float* __restrict__ Q, const float* __restrict__ K, const float* __restrict__ V,
    const __bf16* __restrict__ WT,
    __bf16* __restrict__ qb, __bf16* __restrict__ kb, __bf16* __restrict__ vT)
{
    const int mat = blockIdx.y;
    const float* X = (mat == 0) ? Q : (mat == 1) ? K : V;
    const __bf16* Wt = WT + (size_t)mat * DK_ * DM_;

    const int t    = threadIdx.x;
    const int w    = t >> 6;
    const int l    = t & 63;
    const int quad = l >> 4;
    const int c16  = l & 15;
    const int m0   = blockIdx.x * 64 + w * 16;
    const float* xrow = &X[(size_t)(m0 + c16) * DM_];

    f32x4 acc[8];
    for (int i = 0; i < 8; ++i) acc[i] = {0.f, 0.f, 0.f, 0.f};

    for (int dt = 0; dt < DM_ / 32; ++dt) {
        const int d0 = dt * 32;
        float4 x0 = *(const float4*)(xrow + d0 + quad * 8);
        float4 x1 = *(const float4*)(xrow + d0 + quad * 8 + 4);
        bf16x8 af;
        af[0] = (__bf16)x0.x; af[1] = (__bf16)x0.y; af[2] = (__bf16)x0.z; af[3] = (__bf16)x0.w;
        af[4] = (__bf16)x1.x; af[5] = (__bf16)x1.y; af[6] = (__bf16)x1.z; af[7] = (__bf16)x1.w;
        for (int nt = 0; nt < 8; ++nt) {
            // B[k=d][n]: contiguous 16 B from WT row (n = nt*16+c16)
            bf16x8 bfv = *(const bf16x8*)&Wt[(size_t)(nt * 16 + c16) * DM_ + d0 + quad * 8];
            acc[nt] = __builtin_amdgcn_mfma_f32_16x16x32_bf16(af, bfv, acc[nt], 0, 0, 0);
        }
    }

    // C/D layout: row = quad*4 + r, col = c16 + 16*nt
    if (mat < 2) {
        __bf16* outp = (mat == 0) ? qb : kb;
        for (int nt = 0; nt < 8; ++nt)
            for (int r = 0; r < 4; ++r)
                outp[(size_t)(m0 + quad * 4 + r) * DK_ + nt * 16 + c16] = (__bf16)acc[nt][r];
    } else {
        for (int nt = 0; nt < 8; ++nt)
            for (int r = 0; r < 4; ++r) {
                int row = m0 + quad * 4 + r;            // flat b*L + s
                int b = row >> 12, s = row & (L_ - 1);
                vT[((size_t)b * DV_ + nt * 16 + c16) * L_ + s] = (__bf16)acc[nt][r];
            }
    }
}

// ---------------------------------------------------------------------------
// Kernel 2: flash attention, barrier-free main loop. Block = 4 waves sharing
// the SAME 16 q-rows; wave w owns keys [w*1024, (w+1)*1024). K/V B-frags are
// contiguous 16 B global loads from kb / vT (L2-cached). P round-trips
// through per-wave LDS scratch (aliased over the epilogue o_buf). End: 4
// partial (m,l,o) states merged in LDS. XCD swizzle pins each batch to 2 XCDs.
// ---------------------------------------------------------------------------
__global__ __launch_bounds__(256, 4) void attn_kernel(
    const __bf16* __restrict__ qb, const __bf16* __restrict__ kb,
    const __bf16* __restrict__ vT, const int* __restrict__ mask,
    float* __restrict__ out)
{
    __shared__ float o_buf[4][16][128];         // 32 KB; loop-time alias: P scratch
    __shared__ float comb_m[4][16], comb_l[4][16], Lrow[16];

    const int t    = threadIdx.x;
    const int w    = t >> 6;
    const int l    = t & 63;
    const int quad = l >> 4;
    const int c16  = l & 15;
    // XCD swizzle: batch b -> XCDs {2b, 2b+1}; 2 MB K/V per batch fits 4 MB L2
    const int b    = (blockIdx.x & 7) >> 1;
    const int tile = ((blockIdx.x >> 3) << 1) | (blockIdx.x & 1);
    const int m0   = tile * 16;
    const size_t bL = (size_t)b * L_;

    // per-wave P scratch: 16 rows x 64 cols bf16, row stride 80 (2560 B/wave)
    __bf16* p_lds = (__bf16*)o_buf + w * (16 * 80);

    // q fragments (A-layout: m = lane&15) for the block's 16 rows
    bf16x8 qf[4];
    {
        const __bf16* qrow = &qb[(bL + m0 + c16) * DK_];
        for (int dt = 0; dt < 4; ++dt)
            qf[dt] = *(const bf16x8*)&qrow[dt * 32 + quad * 8];
    }

    f32x4 o[8];
    for (int i = 0; i < 8; ++i) o[i] = {0.f, 0.f, 0.f, 0.f};
    float mst[4], lst[4];
    for (int r = 0; r < 4; ++r) { mst[r] = -1e30f; lst[r] = 0.f; }

    const float sm_scale = 0.088388347648318447f;  // 1/sqrt(DK)
    const int kbase = w * (L_ / 4);

    for (int sc = 0; sc < (L_ / 4) / 64; ++sc) {
        const int s0 = kbase + sc * 64;

        // ---- S = q . k^T  (16 rows x 64 keys), K frags straight from global
        f32x4 sacc[4];
        for (int nt = 0; nt < 4; ++nt) sacc[nt] = {0.f, 0.f, 0.f, 0.f};
        for (int dt = 0; dt < 4; ++dt)
            for (int nt = 0; nt < 4; ++nt) {
                bf16x8 kf = *(const bf16x8*)&kb[(bL + s0 + nt * 16 + c16) * DK_ + dt * 32 + quad * 8];
                sacc[nt] = __builtin_amdgcn_mfma_f32_16x16x32_bf16(qf[dt], kf, sacc[nt], 0, 0, 0);
            }

        // mask (faithful: -inf before scale == -inf after; all-ones here)
        int mk[4];
        for (int nt = 0; nt < 4; ++nt) mk[nt] = mask[bL + s0 + nt * 16 + c16];
        for (int nt = 0; nt < 4; ++nt)
            for (int r = 0; r < 4; ++r) {
                float s = sacc[nt][r] * sm_scale;
                sacc[nt][r] = (mk[nt] == 1) ? s : -1e30f;
            }

        // ---- online softmax; row = quad*4 + r, cols across the 16-lane group
        float alpha[4];
        for (int r = 0; r < 4; ++r) {
            float cm = fmaxf(fmaxf(sacc[0][r], sacc[1][r]), fmaxf(sacc[2][r], sacc[3][r]));
            cm = wred_max16(cm);
            float nm = fmaxf(mst[r], cm);
            alpha[r] = __expf(mst[r] - nm);
            float psum = 0.f;
            for (int nt = 0; nt < 4; ++nt) {
                float p = __expf(sacc[nt][r] - nm);
                __bf16 pbv = (__bf16)p;
                p_lds[(quad * 4 + r) * 80 + nt * 16 + c16] = pbv;  // C-layout -> LDS
                psum += (float)pbv;                                 // sum ROUNDED p
            }
            psum = wred_sum16(psum);
            lst[r] = lst[r] * alpha[r] + psum;
            mst[r] = nm;
        }
        __asm__ volatile("s_waitcnt lgkmcnt(0)" ::: "memory");  // P visible (wave-local)

        for (int vt = 0; vt < 8; ++vt)
            for (int r = 0; r < 4; ++r)
                o[vt][r] *= alpha[r];

        // ---- O += P . V, V frags straight from global vT
        for (int kt = 0; kt < 2; ++kt) {
            bf16x8 pf = *(const bf16x8*)&p_lds[c16 * 80 + kt * 32 + quad * 8];
            for (int vt = 0; vt < 8; ++vt) {
                bf16x8 vf = *(const bf16x8*)&vT[((size_t)b * DV_ + vt * 16 + c16) * L_ + s0 + kt * 32 + quad * 8];
                o[vt] = __builtin_amdgcn_mfma_f32_16x16x32_bf16(pf, vf, o[vt], 0, 0, 0);
            }
        }
    }

    // ---- combine the 4 per-wave partial states ----
    if (c16 == 0)
        for (int r = 0; r < 4; ++r) {
            comb_m[w][quad * 4 + r] = mst[r];
            comb_l[w][quad * 4 + r] = lst[r];
        }
    __syncthreads();   // all waves done looping; o_buf (P alias) now reusable

    float scale[4];
    {
        for (int r = 0; r < 4; ++r) {
            int row = quad * 4 + r;
            float M = fmaxf(fmaxf(comb_m[0][row], comb_m[1][row]),
                            fmaxf(comb_m[2][row], comb_m[3][row]));
            float Lt = comb_l[0][row] * __expf(comb_m[0][row] - M)
                     + comb_l[1][row] * __expf(comb_m[1][row] - M)
                     + comb_l[2][row] * __expf(comb_m[2][row] - M)
                     + comb_l[3][row] * __expf(comb_m[3][row] - M);
            scale[r] = __expf(mst[r] - M);
            if (w == 0 && c16 == 0) Lrow[row] = Lt;
        }
    }
    for (int vt = 0; vt < 8; ++vt)
        for (int r = 0; r < 4; ++r)
            o_buf[w][quad * 4 + r][vt * 16 + c16] = o[vt][r] * scale[r];
    __syncthreads();

    for (int i = 0; i < 8; ++i) {
        int idx = i * 256 + t;
        int row = idx >> 7, col = idx & 127;
        float s = o_buf[0][row][col] + o_buf[1][row][col]
                + o_buf[2][row][col] + o_buf[3][row][col];
        out[(bL + m0 + row) * DV_ + col] = s / Lrow[row];
    }
}

extern "C" void kernel_launch(void* const* d_in, const int* in_sizes, int n_in,
                              void* d_out, int out_size, void* d_ws, size_t ws_size,
                              hipStream_t stream) {
    const float* Q    = (const float*)d_in[0];
    const float* K    = (const float*)d_in[1];
    const float* V    = (const float*)d_in[2];
    const int*   mask = (const int*)d_in[3];
    const float* WQ   = (const float*)d_in[4];
    const float* WK   = (const float*)d_in[5];
    const float* WV   = (const float*)d_in[6];
    float* out = (float*)d_out;

    // workspace: qb (4MB) | kb (4MB) | vT (4MB) | WT (0.75MB)
    __bf16* qb = (__bf16*)d_ws;
    __bf16* kb = qb + (size_t)B_ * L_ * DK_;
    __bf16* vT = kb + (size_t)B_ * L_ * DK_;
    __bf16* WT = vT + (size_t)B_ * L_ * DV_;

    wt_kernel<<<dim3(DM_ / 32, 3), 256, 0, stream>>>(WQ, WK, WV, WT);
    proj_kernel<<<dim3((B_ * L_) / 64, 3), 256, 0, stream>>>(Q, K, V, WT, qb, kb, vT);
    attn_kernel<<<dim3(B_ * L_ / 16), 256, 0, stream>>>(qb, kb, vT, mask, out);
}

// Round 3
// 335.044 us; speedup vs baseline: 1.6442x; 1.5164x over previous
//
#include <hip/hip_runtime.h>
#include <hip/hip_bf16.h>

#define B_  4
#define L_  4096
#define DM_ 1024
#define DK_ 128
#define DV_ 128
#define KS_ 4                      // key-splits across blocks
#define ROWS_ (B_ * L_)            // 16384

typedef __bf16 bf16x8 __attribute__((ext_vector_type(8)));
typedef float  f32x4  __attribute__((ext_vector_type(4)));

__device__ __forceinline__ float wred_max16(float v) {
    v = fmaxf(v, __shfl_xor(v, 1, 64));
    v = fmaxf(v, __shfl_xor(v, 2, 64));
    v = fmaxf(v, __shfl_xor(v, 4, 64));
    v = fmaxf(v, __shfl_xor(v, 8, 64));
    return v;
}
__device__ __forceinline__ float wred_sum16(float v) {
    v += __shfl_xor(v, 1, 64);
    v += __shfl_xor(v, 2, 64);
    v += __shfl_xor(v, 4, 64);
    v += __shfl_xor(v, 8, 64);
    return v;
}

// ---------------------------------------------------------------------------
// Kernel 0: transpose+cast W (1024x128 fp32) -> WT (128x1024 bf16), 3 mats.
// ---------------------------------------------------------------------------
__global__ __launch_bounds__(256) void wt_kernel(
    const float* __restrict__ WQ, const float* __restrict__ WK,
    const float* __restrict__ WV, __bf16* __restrict__ WT)
{
    const int mat = blockIdx.y;
    const float* W = (mat == 0) ? WQ : (mat == 1) ? WK : WV;
    __bf16* Wt = WT + (size_t)mat * DK_ * DM_;

    __shared__ float lds[DK_][33];
    const int t  = threadIdx.x;
    const int d0 = blockIdx.x * 32;

    for (int i = 0; i < 16; ++i) {
        int idx = i * 256 + t;
        int dd = idx >> 7, n = idx & 127;
        lds[n][dd] = W[(size_t)(d0 + dd) * DK_ + n];
    }
    __syncthreads();
    for (int i = 0; i < 16; ++i) {
        int idx = i * 256 + t;
        int n = idx >> 5, dd = idx & 31;
        Wt[(size_t)n * DM_ + d0 + dd] = (__bf16)lds[n][dd];
    }
}

// ---------------------------------------------------------------------------
// Kernel 1: projections, m97-style. BK=128: stage WT chunk [128 n][128 d]
// (32 KB, dense-line loads, shared by 4 waves) once per 8 K-steps; X rows
// loaded direct (dense 128 B line segments). Pad 132 -> frag-read banks
// (2*c16+4*quad) = 2-way (free). 16 barriers/block (was 64).
// ---------------------------------------------------------------------------
__global__ __launch_bounds__(256) void proj_kernel(
    const float* __restrict__ Q, const float* __restrict__ K, const float* __restrict__ V,
    const __bf16* __restrict__ WT,
    __bf16* __restrict__ qb, __bf16* __restrict__ kb, __bf16* __restrict__ vT)
{
    const int mat = blockIdx.y;
    const float* X = (mat == 0) ? Q : (mat == 1) ? K : V;
    const __bf16* Wt = WT + (size_t)mat * DK_ * DM_;

    __shared__ __bf16 w_lds[128][132];            // 33792 B -> 4 blocks/CU

    const int t    = threadIdx.x;
    const int w    = t >> 6;
    const int l    = t & 63;
    const int quad = l >> 4;
    const int c16  = l & 15;
    const int m0   = blockIdx.x * 64 + w * 16;
    const float* xrow = &X[(size_t)(m0 + c16) * DM_];

    f32x4 acc[8];
    for (int i = 0; i < 8; ++i) acc[i] = {0.f, 0.f, 0.f, 0.f};

    for (int kt8 = 0; kt8 < 8; ++kt8) {           // BK = 128
        const int d0 = kt8 * 128;
        __syncthreads();
        // stage WT[0:128][d0:d0+128]: 2048 x 16 B, dense 256 B row segments
        for (int i = 0; i < 8; ++i) {
            int e = i * 256 + t;
            int n = e >> 4, blk = e & 15;
            *(int4*)&w_lds[n][blk * 8] = *(const int4*)&Wt[(size_t)n * DM_ + d0 + blk * 8];
        }
        __syncthreads();

        for (int dd = 0; dd < 4; ++dd) {
            const float* xp = xrow + d0 + dd * 32 + quad * 8;
            float4 x0 = *(const float4*)xp;
            float4 x1 = *(const float4*)(xp + 4);
            bf16x8 af;
            af[0] = (__bf16)x0.x; af[1] = (__bf16)x0.y; af[2] = (__bf16)x0.z; af[3] = (__bf16)x0.w;
            af[4] = (__bf16)x1.x; af[5] = (__bf16)x1.y; af[6] = (__bf16)x1.z; af[7] = (__bf16)x1.w;
            for (int nt = 0; nt < 8; ++nt) {
                bf16x8 bfv = *(const bf16x8*)&w_lds[nt * 16 + c16][dd * 32 + quad * 8];
                acc[nt] = __builtin_amdgcn_mfma_f32_16x16x32_bf16(af, bfv, acc[nt], 0, 0, 0);
            }
        }
    }

    // C/D layout: row = quad*4 + r, col = c16 + 16*nt
    if (mat < 2) {
        __bf16* outp = (mat == 0) ? qb : kb;
        for (int nt = 0; nt < 8; ++nt)
            for (int r = 0; r < 4; ++r)
                outp[(size_t)(m0 + quad * 4 + r) * DK_ + nt * 16 + c16] = (__bf16)acc[nt][r];
    } else {
        for (int nt = 0; nt < 8; ++nt)
            for (int r = 0; r < 4; ++r) {
                int row = m0 + quad * 4 + r;
                int b = row >> 12, s = row & (L_ - 1);
                vT[((size_t)b * DV_ + nt * 16 + c16) * L_ + s] = (__bf16)acc[nt][r];
            }
    }
}

// ---------------------------------------------------------------------------
// Kernel 2: flash attention. 4 waves share LDS-staged 64-key chunks (K and
// transposed V), each wave owns 16 of the block's 64 q-rows; all waves walk
// the block's 1024-key range (KS=4 split across blocks -> bf16 partials +
// combine kernel). Staging = vectorized VGPR roundtrip into pad-tuned LDS
// (stride 140/76 elem -> frag reads 2-way banks = free). XCD pinning: each
// XCD sees 1 batch x 2 key ranges = 1 MB (L2-resident).
// ---------------------------------------------------------------------------
__global__ __launch_bounds__(256) void attn_kernel(
    const __bf16* __restrict__ qb, const __bf16* __restrict__ kb,
    const __bf16* __restrict__ vT, const int* __restrict__ mask,
    __bf16* __restrict__ ob_part, float* __restrict__ ml_part)
{
    __shared__ __bf16 k_lds[64][140];      // 17920 B
    __shared__ __bf16 v_lds[128][76];      // 19456 B
    __shared__ __bf16 p_lds[4][16][76];    //  9728 B   (total 47104 -> 3 blk/CU)

    const int t    = threadIdx.x;
    const int w    = t >> 6;
    const int l    = t & 63;
    const int quad = l >> 4;
    const int c16  = l & 15;

    const int combo = blockIdx.x & 15;     // xcd = blockIdx%8: 1 batch, 2 ranges
    const int b     = combo & 3;
    const int ks    = combo >> 2;
    const int qt    = blockIdx.x >> 4;     // 0..63
    const int m0    = qt * 64 + w * 16;    // wave's q-rows (within batch)
    const size_t bL = (size_t)b * L_;
    const int kbase = ks * (L_ / KS_);     // 1024-key range

    bf16x8 qf[4];
    {
        const __bf16* qrow = &qb[(bL + m0 + c16) * DK_];
        for (int dt = 0; dt < 4; ++dt)
            qf[dt] = *(const bf16x8*)&qrow[dt * 32 + quad * 8];
    }

    f32x4 o[8];
    for (int i = 0; i < 8; ++i) o[i] = {0.f, 0.f, 0.f, 0.f};
    float mst[4], lst[4];
    for (int r = 0; r < 4; ++r) { mst[r] = -1e30f; lst[r] = 0.f; }

    const float sm_scale = 0.088388347648318447f;  // 1/sqrt(DK)

    for (int sc = 0; sc < (L_ / KS_) / 64; ++sc) {  // 16 chunks
        const int s0 = kbase + sc * 64;
        __syncthreads();                   // prev chunk's frag reads done
        // stage K chunk (64 x 128): 1024 x 16 B dense
        for (int i = 0; i < 4; ++i) {
            int e = i * 256 + t;
            int kr = e >> 4, c8 = (e & 15) << 3;
            *(int4*)&k_lds[kr][c8] = *(const int4*)&kb[(bL + s0 + kr) * DK_ + c8];
        }
        // stage vT chunk (128 x 64): dense 128 B row segments
        for (int i = 0; i < 4; ++i) {
            int e = i * 256 + t;
            int vr = e >> 3, s8 = (e & 7) << 3;
            *(int4*)&v_lds[vr][s8] = *(const int4*)&vT[((size_t)b * DV_ + vr) * L_ + s0 + s8];
        }
        __syncthreads();

        // ---- S = q . k^T ----
        f32x4 sacc[4];
        for (int nt = 0; nt < 4; ++nt) sacc[nt] = {0.f, 0.f, 0.f, 0.f};
        for (int dt = 0; dt < 4; ++dt)
            for (int nt = 0; nt < 4; ++nt) {
                bf16x8 kf = *(const bf16x8*)&k_lds[nt * 16 + c16][dt * 32 + quad * 8];
                sacc[nt] = __builtin_amdgcn_mfma_f32_16x16x32_bf16(qf[dt], kf, sacc[nt], 0, 0, 0);
            }

        int mk[4];
        for (int nt = 0; nt < 4; ++nt) mk[nt] = mask[bL + s0 + nt * 16 + c16];
        for (int nt = 0; nt < 4; ++nt)
            for (int r = 0; r < 4; ++r) {
                float s = sacc[nt][r] * sm_scale;
                sacc[nt][r] = (mk[nt] == 1) ? s : -1e30f;
            }

        // ---- online softmax ----
        float alpha[4];
        for (int r = 0; r < 4; ++r) {
            float cm = fmaxf(fmaxf(sacc[0][r], sacc[1][r]), fmaxf(sacc[2][r], sacc[3][r]));
            cm = wred_max16(cm);
            float nm = fmaxf(mst[r], cm);
            alpha[r] = __expf(mst[r] - nm);
            float psum = 0.f;
            for (int nt = 0; nt < 4; ++nt) {
                float p = __expf(sacc[nt][r] - nm);
                __bf16 pbv = (__bf16)p;
                p_lds[w][quad * 4 + r][nt * 16 + c16] = pbv;
                psum += (float)pbv;        // sum the ROUNDED p (consistency)
            }
            psum = wred_sum16(psum);
            lst[r] = lst[r] * alpha[r] + psum;
            mst[r] = nm;
        }
        __asm__ volatile("s_waitcnt lgkmcnt(0)" ::: "memory");

        for (int vt = 0; vt < 8; ++vt)
            for (int r = 0; r < 4; ++r)
                o[vt][r] *= alpha[r];

        // ---- O += P . V ----
        for (int kt = 0; kt < 2; ++kt) {
            bf16x8 pf = *(const bf16x8*)&p_lds[w][c16][kt * 32 + quad * 8];
            for (int vt = 0; vt < 8; ++vt) {
                bf16x8 vf = *(const bf16x8*)&v_lds[vt * 16 + c16][kt * 32 + quad * 8];
                o[vt] = __builtin_amdgcn_mfma_f32_16x16x32_bf16(pf, vf, o[vt], 0, 0, 0);
            }
        }
    }

    // ---- write this split's partial (unnormalized o, m, l) ----
    __bf16* op = ob_part + ((size_t)ks * ROWS_ + bL + m0) * DV_;
    for (int vt = 0; vt < 8; ++vt)
        for (int r = 0; r < 4; ++r)
            op[(size_t)(quad * 4 + r) * DV_ + vt * 16 + c16] = (__bf16)o[vt][r];
    if (c16 == 0)
        for (int r = 0; r < 4; ++r) {
            size_t row = (size_t)ks * ROWS_ + bL + m0 + quad * 4 + r;
            ml_part[row * 2 + 0] = mst[r];
            ml_part[row * 2 + 1] = lst[r];
        }
}

// ---------------------------------------------------------------------------
// Kernel 3: combine KS partials. thread -> (row, 4 cols). fp32 accumulate.
// ---------------------------------------------------------------------------
__global__ __launch_bounds__(256) void combine_kernel(
    const __bf16* __restrict__ ob_part, const float* __restrict__ ml_part,
    float* __restrict__ out)
{
    const int gid = blockIdx.x * 256 + threadIdx.x;     // ROWS_*32
    const int row = gid >> 5;
    const int c4  = (gid & 31) << 2;

    float m[KS_], lv[KS_];
    float M = -1e30f;
    for (int s = 0; s < KS_; ++s) {
        m[s]  = ml_part[((size_t)s * ROWS_ + row) * 2 + 0];
        lv[s] = ml_part[((size_t)s * ROWS_ + row) * 2 + 1];
        M = fmaxf(M, m[s]);
    }
    float Lt = 0.f, acc[4] = {0.f, 0.f, 0.f, 0.f};
    for (int s = 0; s < KS_; ++s) {
        float ws = __expf(m[s] - M);
        Lt += lv[s] * ws;
        const __bf16* op = ob_part + ((size_t)s * ROWS_ + row) * DV_ + c4;
        for (int c = 0; c < 4; ++c) acc[c] += (float)op[c] * ws;
    }
    float rL = 1.0f / Lt;
    for (int c = 0; c < 4; ++c)
        out[(size_t)row * DV_ + c4 + c] = acc[c] * rL;
}

extern "C" void kernel_launch(void* const* d_in, const int* in_sizes, int n_in,
                              void* d_out, int out_size, void* d_ws, size_t ws_size,
                              hipStream_t stream) {
    const float* Q    = (const float*)d_in[0];
    const float* K    = (const float*)d_in[1];
    const float* V    = (const float*)d_in[2];
    const int*   mask = (const int*)d_in[3];
    const float* WQ   = (const float*)d_in[4];
    const float* WK   = (const float*)d_in[5];
    const float* WV   = (const float*)d_in[6];
    float* out = (float*)d_out;

    // ws: qb 4MB | kb 4MB | vT 4MB | WT 0.75MB | ob_part 16MB | ml 0.5MB
    __bf16* qb = (__bf16*)d_ws;
    __bf16* kb = qb + (size_t)ROWS_ * DK_;
    __bf16* vT = kb + (size_t)ROWS_ * DK_;
    __bf16* WT = vT + (size_t)ROWS_ * DV_;
    __bf16* ob_part = WT + (size_t)3 * DK_ * DM_;
    float*  ml_part = (float*)(ob_part + (size_t)KS_ * ROWS_ * DV_);

    wt_kernel<<<dim3(DM_ / 32, 3), 256, 0, stream>>>(WQ, WK, WV, WT);
    proj_kernel<<<dim3(ROWS_ / 64, 3), 256, 0, stream>>>(Q, K, V, WT, qb, kb, vT);
    attn_kernel<<<dim3((ROWS_ / 64) * KS_), 256, 0, stream>>>(qb, kb, vT, mask, ob_part, ml_part);
    combine_kernel<<<dim3(ROWS_ * 32 / 256), 256, 0, stream>>>(ob_part, ml_part, out);
}